// Round 8
// baseline (53.024 us; speedup 1.0000x reference)
//
#include <hip/hip_runtime.h>
#include <stdint.h>

#define NQ 900
#define TOPK_PRE 100
#define TOPK_POST 20
#define IOU_THR 0.7f

typedef unsigned long long u64;

__device__ __forceinline__ u64 umin64(u64 a, u64 b) { return a < b ? a : b; }
__device__ __forceinline__ u64 umax64(u64 a, u64 b) { return a > b ? a : b; }

__device__ __forceinline__ float rlf(float v, int l) {
    return __uint_as_float(__builtin_amdgcn_readlane(__float_as_uint(v), l));
}

// One bitonic level (size K) applied to 8 independent 128-element blocks,
// each block = reg pair (2r,2r+1), element index el = (r&1)*64 + lane.
template<int K>
__device__ __forceinline__ void blk_level(u64 (&kr)[16], int lane) {
    if constexpr (K == 128) {            // j = 64: reg-local pair CE (ascending)
#pragma unroll
        for (int r = 0; r < 16; r += 2) {
            u64 lo = umin64(kr[r], kr[r + 1]);
            u64 hi = umax64(kr[r], kr[r + 1]);
            kr[r] = lo; kr[r + 1] = hi;
        }
    }
    const int J0 = (K >= 64) ? 32 : (K / 2);
#pragma clang loop unroll(disable)
    for (int j = J0; j > 0; j >>= 1) {
#pragma unroll
        for (int r = 0; r < 16; ++r) {
            u64 part = __shfl_xor(kr[r], j);
            int el = ((r & 1) << 6) | lane;
            bool up = ((el & K) == 0);
            bool lower = ((lane & j) == 0);
            kr[r] = (up == lower) ? umin64(kr[r], part) : umax64(kr[r], part);
        }
    }
}

// ascending bitonic-merge descent on a 128-elem bitonic sequence in (c0,c1)
__device__ __forceinline__ void merge_desc(u64& c0, u64& c1, int lane) {
    u64 lo = umin64(c0, c1), hi = umax64(c0, c1);   // j = 64 (reg-local)
    c0 = lo; c1 = hi;
#pragma clang loop unroll(disable)
    for (int j = 32; j > 0; j >>= 1) {
        bool lower = (lane & j) == 0;
        u64 p0 = __shfl_xor(c0, j);
        u64 p1 = __shfl_xor(c1, j);
        c0 = lower ? umin64(c0, p0) : umax64(c0, p0);
        c1 = lower ? umin64(c1, p1) : umax64(c1, p1);
    }
}

// (a0,a1),(b0,b1) sorted asc -> (a0,a1) = sorted asc 128 smallest of union
__device__ __forceinline__ void merge128(u64& a0, u64& a1, u64 b0, u64 b1, int lane) {
    u64 m0 = __shfl_xor(b1, 63);        // B[127-e] for e in 0..63
    u64 m1 = __shfl_xor(b0, 63);        // B[127-e] for e in 64..127
    a0 = umin64(a0, m0);
    a1 = umin64(a1, m1);
    merge_desc(a0, a1, lane);
}

// Output layout (float32):
//   sel_s : [0,      20480)   (16,64,20)
//   sel_b : [20480, 102400)   (16,64,20,4)
//   sel_l : [102400,122880)   (16,64,20)
//   vmask : [122880,143360)   (16,64,20)

__global__ __launch_bounds__(64)
void ovnms_kernel(const float* __restrict__ logits,   // (16,1,57600,2)
                  const float* __restrict__ boxes,    // (16,1,57600,4)
                  const float* __restrict__ tsize,    // (16,2) [h,w]
                  const int*   __restrict__ labels,   // (16,64)
                  float* __restrict__ out)
{
#pragma clang fp contract(off)
    const int row  = blockIdx.x;       // b*64 + p
    const int b    = row >> 6;
    const int p    = row & 63;
    const int lane = threadIdx.x;      // 0..63, one wave per block/row

    __shared__ float x1s[TOPK_PRE], y1s[TOPK_PRE], x2s[TOPK_PRE], y2s[TOPK_PRE];
    __shared__ float scs[TOPK_PRE];

    // ---- 1. sigmoid scores -> 16 keys per lane (whole row in one wave) ----
    const float* lrow = logits + ((size_t)b * 57600 + (size_t)p * NQ) * 2;
    u64 kr[16];
#pragma unroll
    for (int r = 0; r < 16; ++r) {
        int q = r * 64 + lane;
        u64 key = ~0ull;
        if (q < NQ) {
            float x = lrow[q * 2 + 1];           // channel -1 == 1
            float s = 1.0f / (1.0f + expf(-x));
            unsigned u = __float_as_uint(s);
            key = ((u64)(~u) << 32) | (unsigned)q;
        }
        kr[r] = key;
    }

    // ---- 2. sort 8 blocks of 128 ascending (register-virtualized bitonic) ----
    blk_level<2>(kr, lane);
    blk_level<4>(kr, lane);
    blk_level<8>(kr, lane);
    blk_level<16>(kr, lane);
    blk_level<32>(kr, lane);
    blk_level<64>(kr, lane);
    blk_level<128>(kr, lane);

    // ---- 3. top-128 via mirrored min-merges: 8 -> 4 -> 2 -> 1 blocks ----
    merge128(kr[0],  kr[1],  kr[2],  kr[3],  lane);
    merge128(kr[4],  kr[5],  kr[6],  kr[7],  lane);
    merge128(kr[8],  kr[9],  kr[10], kr[11], lane);
    merge128(kr[12], kr[13], kr[14], kr[15], lane);
    merge128(kr[0],  kr[1],  kr[4],  kr[5],  lane);
    merge128(kr[8],  kr[9],  kr[12], kr[13], lane);
    merge128(kr[0],  kr[1],  kr[8],  kr[9],  lane);
    // kr[0] = ranks 0..63 (lane), kr[1] = ranks 64..127

    // ---- 4. gather candidate boxes: slot A = rank lane, slot B = rank 64+lane ----
    const float ih = tsize[b * 2 + 0];
    const float iw = tsize[b * 2 + 1];
    const size_t brow0 = (size_t)b * 57600 + (size_t)p * NQ;

    int qa = (int)(kr[0] & 0xFFFFFFFFu);
    float sa = __uint_as_float(~(unsigned)(kr[0] >> 32));
    const float* ba = boxes + (brow0 + (size_t)qa) * 4;
    float cx = ba[0], cy = ba[1], w = ba[2], h = ba[3];
    float ax1 = (cx - 0.5f * w) * iw;
    float ay1 = (cy - 0.5f * h) * ih;
    float ax2 = (cx + 0.5f * w) * iw;
    float ay2 = (cy + 0.5f * h) * ih;
    float aar = fmaxf(ax2 - ax1, 0.0f) * fmaxf(ay2 - ay1, 0.0f);
    x1s[lane] = ax1; y1s[lane] = ay1; x2s[lane] = ax2; y2s[lane] = ay2;
    scs[lane] = sa;

    const bool hb = lane < (TOPK_PRE - 64);   // lanes 0..35 own ranks 64..99
    float bx1 = 0.0f, by1 = 0.0f, bx2 = 0.0f, by2 = 0.0f, bar = 0.0f;
    if (hb) {
        int qb = (int)(kr[1] & 0xFFFFFFFFu);
        float sb = __uint_as_float(~(unsigned)(kr[1] >> 32));
        const float* bb = boxes + (brow0 + (size_t)qb) * 4;
        float cx2 = bb[0], cy2 = bb[1], w2 = bb[2], h2 = bb[3];
        bx1 = (cx2 - 0.5f * w2) * iw;
        by1 = (cy2 - 0.5f * h2) * ih;
        bx2 = (cx2 + 0.5f * w2) * iw;
        by2 = (cy2 + 0.5f * h2) * ih;
        bar = fmaxf(bx2 - bx1, 0.0f) * fmaxf(by2 - by1, 0.0f);
        x1s[64 + lane] = bx1; y1s[64 + lane] = by1;
        x2s[64 + lane] = bx2; y2s[64 + lane] = by2;
        scs[64 + lane] = sb;
    }

    // ---- 5. fused greedy NMS: ballot + readlane, all in registers ----
    bool alive_a = true;
    bool alive_b = hb;

#pragma clang loop unroll(disable)
    for (int i = 0; i < 64; ++i) {
        u64 bal = __ballot(alive_a);
        if ((bal >> i) & 1ull) {               // candidate i alive (uniform branch)
            float xi1 = rlf(ax1, i), yi1 = rlf(ay1, i);
            float xi2 = rlf(ax2, i), yi2 = rlf(ay2, i), ai = rlf(aar, i);
            {   // slot A: j = lane, suppressed only when j > i
                float ltx = fmaxf(xi1, ax1), lty = fmaxf(yi1, ay1);
                float rbx = fminf(xi2, ax2), rby = fminf(yi2, ay2);
                float wx = fmaxf(rbx - ltx, 0.0f), wy = fmaxf(rby - lty, 0.0f);
                float inter = wx * wy;
                float iou = inter / (((ai + aar) - inter) + 1e-7f);
                alive_a = alive_a && !((lane > i) && (iou > IOU_THR));
            }
            {   // slot B: j = 64+lane > i always
                float ltx = fmaxf(xi1, bx1), lty = fmaxf(yi1, by1);
                float rbx = fminf(xi2, bx2), rby = fminf(yi2, by2);
                float wx = fmaxf(rbx - ltx, 0.0f), wy = fmaxf(rby - lty, 0.0f);
                float inter = wx * wy;
                float iou = inter / (((ai + bar) - inter) + 1e-7f);
                alive_b = alive_b && !(iou > IOU_THR);
            }
        }
    }
#pragma clang loop unroll(disable)
    for (int i = 64; i < TOPK_PRE; ++i) {
        u64 bal = __ballot(alive_b);
        if ((bal >> (i - 64)) & 1ull) {
            float xi1 = rlf(bx1, i - 64), yi1 = rlf(by1, i - 64);
            float xi2 = rlf(bx2, i - 64), yi2 = rlf(by2, i - 64), ai = rlf(bar, i - 64);
            float ltx = fmaxf(xi1, bx1), lty = fmaxf(yi1, by1);
            float rbx = fminf(xi2, bx2), rby = fminf(yi2, by2);
            float wx = fmaxf(rbx - ltx, 0.0f), wy = fmaxf(rby - lty, 0.0f);
            float inter = wx * wy;
            float iou = inter / (((ai + bar) - inter) + 1e-7f);
            alive_b = alive_b && !((lane > (i - 64)) && (iou > IOU_THR));
        }
    }
    const u64 K0 = __ballot(alive_a);
    const u64 K1 = __ballot(alive_b);

    // ---- 6. write outputs: lane t takes the t-th kept candidate ----
    if (lane < TOPK_POST) {
        int c0 = __popcll(K0);
        int idx = -1;
        if (lane < c0) {
            u64 x = K0;
#pragma clang loop unroll(disable)
            for (int k = 0; k < lane; ++k) x &= x - 1;
            idx = __ffsll(x) - 1;
        } else {
            int t = lane - c0;
            if (t < __popcll(K1)) {
                u64 x = K1;
#pragma clang loop unroll(disable)
                for (int k = 0; k < t; ++k) x &= x - 1;
                idx = 64 + __ffsll(x) - 1;
            }
        }
        size_t o = (size_t)row * TOPK_POST + (size_t)lane;
        float s = 0.0f, xa = 0.0f, ya = 0.0f, xb = 0.0f, yb = 0.0f;
        float lab = -1.0f, m = 0.0f;
        if (idx >= 0) {
            s = scs[idx];
            xa = x1s[idx]; ya = y1s[idx]; xb = x2s[idx]; yb = y2s[idx];
            lab = (float)labels[row];
            m = 1.0f;
        }
        out[o] = s;
        float* ob = out + 20480 + o * 4;
        ob[0] = xa; ob[1] = ya; ob[2] = xb; ob[3] = yb;
        out[102400 + o] = lab;
        out[122880 + o] = m;
    }
}

extern "C" void kernel_launch(void* const* d_in, const int* in_sizes, int n_in,
                              void* d_out, int out_size, void* d_ws, size_t ws_size,
                              hipStream_t stream) {
    const float* logits = (const float*)d_in[0];
    const float* boxes  = (const float*)d_in[1];
    const float* tsize  = (const float*)d_in[2];
    const int*   labels = (const int*)d_in[3];
    float* out = (float*)d_out;

    ovnms_kernel<<<dim3(1024), dim3(64), 0, stream>>>(logits, boxes, tsize, labels, out);
}

// Round 9
// 34.417 us; speedup vs baseline: 1.5407x; 1.5407x over previous
//
#include <hip/hip_runtime.h>
#include <stdint.h>

#define NQ 900
#define TOPK_PRE 100
#define TOPK_POST 20
#define IOU_THR 0.7f
#define THREADS 512

typedef unsigned long long u64;

__device__ __forceinline__ u64 umin64(u64 a, u64 b) { return a < b ? a : b; }
__device__ __forceinline__ u64 umax64(u64 a, u64 b) { return a > b ? a : b; }

__device__ __forceinline__ void ce(u64& v, int j, bool up, int lane) {
    u64 part = __shfl_xor(v, j);
    bool lower = ((lane & j) == 0);
    v = (up == lower) ? umin64(v, part) : umax64(v, part);
}

// merge two sorted-ascending 128-lists (in LDS) -> sorted ascending top-128 in (c0,c1)
__device__ __forceinline__ void merge_lds(const u64* __restrict__ A,
                                          const u64* __restrict__ B,
                                          u64& c0, u64& c1, int lane) {
    c0 = umin64(A[lane],      B[127 - lane]);
    c1 = umin64(A[64 + lane], B[63 - lane]);
    u64 lo = umin64(c0, c1), hi = umax64(c0, c1);   // j = 64 (reg-local)
    c0 = lo; c1 = hi;
#pragma unroll
    for (int j = 32; j > 0; j >>= 1) {
        bool lower = (lane & j) == 0;
        u64 p0 = __shfl_xor(c0, j);
        u64 p1 = __shfl_xor(c1, j);
        c0 = lower ? umin64(c0, p0) : umax64(c0, p0);
        c1 = lower ? umin64(c1, p1) : umax64(c1, p1);
    }
}

// Output layout (float32):
//   sel_s : [0,      20480)   (16,64,20)
//   sel_b : [20480, 102400)   (16,64,20,4)
//   sel_l : [102400,122880)   (16,64,20)
//   vmask : [122880,143360)   (16,64,20)

__global__ __launch_bounds__(THREADS)
void ovnms_kernel(const float* __restrict__ logits,   // (16,1,57600,2)
                  const float* __restrict__ boxes,    // (16,1,57600,4)
                  const float* __restrict__ tsize,    // (16,2) [h,w]
                  const int*   __restrict__ labels,   // (16,64)
                  float* __restrict__ out)
{
#pragma clang fp contract(off)
    const int row  = blockIdx.x;       // b*64 + p
    const int b    = row >> 6;
    const int p    = row & 63;
    const int tid  = threadIdx.x;
    const int lane = tid & 63;
    const int wid  = tid >> 6;         // 0..7

    __shared__ u64 wl[8 * 128];        // per-wave sorted 128-lists
    __shared__ u64 md[4 * 128];        // round-1 results
    __shared__ u64 m2[2 * 128];        // round-2 results
    __shared__ u64 fin[128];           // final sorted top-128
    __shared__ float x1s[TOPK_PRE], y1s[TOPK_PRE], x2s[TOPK_PRE], y2s[TOPK_PRE];
    __shared__ float areas[TOPK_PRE], scs[TOPK_PRE];
    __shared__ u64 sup0[TOPK_PRE], sup1[TOPK_PRE];
    __shared__ u64 keep0s, keep1s;

    // ---- 1. sigmoid scores -> 2 keys per lane (wave owns queries wid*128..wid*128+127) ----
    const float* lrow = logits + ((size_t)b * 57600 + (size_t)p * NQ) * 2;
    u64 c0, c1;
    {
        int q0 = wid * 128 + lane;
        int q1 = q0 + 64;
        u64 k0 = ~0ull, k1 = ~0ull;
        if (q0 < NQ) {
            float x = lrow[q0 * 2 + 1];
            float s = 1.0f / (1.0f + expf(-x));
            k0 = ((u64)(~__float_as_uint(s)) << 32) | (unsigned)q0;
        }
        if (q1 < NQ) {
            float x = lrow[q1 * 2 + 1];
            float s = 1.0f / (1.0f + expf(-x));
            k1 = ((u64)(~__float_as_uint(s)) << 32) | (unsigned)q1;
        }
        c0 = k0; c1 = k1;
    }

    // ---- 2. in-wave bitonic sort of 128 keys ascending (2 regs, 55 CEs) ----
#pragma unroll
    for (int k = 2; k <= 64; k <<= 1) {
#pragma unroll
        for (int j = k >> 1; j > 0; j >>= 1) {
            ce(c0, j, (lane & k) == 0, lane);
            ce(c1, j, ((64 + lane) & k) == 0, lane);
        }
    }
    {   // k = 128: j=64 reg-local, then j=32..1, ascending everywhere
        u64 lo = umin64(c0, c1), hi = umax64(c0, c1);
        c0 = lo; c1 = hi;
#pragma unroll
        for (int j = 32; j > 0; j >>= 1) {
            ce(c0, j, true, lane);
            ce(c1, j, true, lane);
        }
    }

    wl[wid * 128 + lane]      = c0;
    wl[wid * 128 + 64 + lane] = c1;
    __syncthreads();

    // ---- 3. merge tree 8 -> 4 -> 2 -> 1 ----
    if (wid < 4) {
        u64 a0, a1;
        merge_lds(&wl[(2 * wid) * 128], &wl[(2 * wid + 1) * 128], a0, a1, lane);
        md[wid * 128 + lane]      = a0;
        md[wid * 128 + 64 + lane] = a1;
    }
    __syncthreads();
    if (wid < 2) {
        u64 a0, a1;
        merge_lds(&md[(2 * wid) * 128], &md[(2 * wid + 1) * 128], a0, a1, lane);
        m2[wid * 128 + lane]      = a0;
        m2[wid * 128 + 64 + lane] = a1;
    }
    __syncthreads();
    if (wid == 0) {
        u64 a0, a1;
        merge_lds(m2, m2 + 128, a0, a1, lane);
        fin[lane]      = a0;
        fin[64 + lane] = a1;
    }
    __syncthreads();

    // ---- 4. gather top-100 boxes, scale, areas ----
    if (tid < TOPK_PRE) {
        u64 key = fin[tid];
        int q = (int)(key & 0xFFFFFFFFu);
        scs[tid] = __uint_as_float(~(unsigned)(key >> 32));
        const float* brow = boxes + ((size_t)b * 57600 + (size_t)p * NQ + (size_t)q) * 4;
        float cx = brow[0], cy = brow[1], w = brow[2], h = brow[3];
        float ih = tsize[b * 2 + 0];
        float iw = tsize[b * 2 + 1];
        float xa = (cx - 0.5f * w) * iw;
        float ya = (cy - 0.5f * h) * ih;
        float xb = (cx + 0.5f * w) * iw;
        float yb = (cy + 0.5f * h) * ih;
        x1s[tid] = xa; y1s[tid] = ya; x2s[tid] = xb; y2s[tid] = yb;
        areas[tid] = fmaxf(xb - xa, 0.0f) * fmaxf(yb - ya, 0.0f);
    }
    __syncthreads();

    // ---- 5. suppression bit-matrix via ballot (8 waves, stride 8) ----
    {
        const float xj1a = x1s[lane], yj1a = y1s[lane];
        const float xj2a = x2s[lane], yj2a = y2s[lane], aja = areas[lane];
        const int  j2   = lane + 64;
        const bool hv2  = j2 < TOPK_PRE;
        const int  j2c  = hv2 ? j2 : 0;
        const float xj1b = x1s[j2c], yj1b = y1s[j2c];
        const float xj2b = x2s[j2c], yj2b = y2s[j2c], ajb = areas[j2c];

#pragma unroll 4
        for (int i = wid; i < TOPK_PRE; i += 8) {
            float xi1 = x1s[i], yi1 = y1s[i], xi2 = x2s[i], yi2 = y2s[i], ai = areas[i];
            bool b0 = false;
            if (lane < i) {
                float ltx = fmaxf(xi1, xj1a);
                float lty = fmaxf(yi1, yj1a);
                float rbx = fminf(xi2, xj2a);
                float rby = fminf(yi2, yj2a);
                float wx = fmaxf(rbx - ltx, 0.0f);
                float wy = fmaxf(rby - lty, 0.0f);
                float inter = wx * wy;
                float iou = inter / (((ai + aja) - inter) + 1e-7f);
                b0 = iou > IOU_THR;
            }
            u64 m0 = __ballot(b0);
            bool b1 = false;
            if (hv2 && j2 < i) {
                float ltx = fmaxf(xi1, xj1b);
                float lty = fmaxf(yi1, yj1b);
                float rbx = fminf(xi2, xj2b);
                float rby = fminf(yi2, yj2b);
                float wx = fmaxf(rbx - ltx, 0.0f);
                float wy = fmaxf(rby - lty, 0.0f);
                float inter = wx * wy;
                float iou = inter / (((ai + ajb) - inter) + 1e-7f);
                b1 = iou > IOU_THR;
            }
            u64 m1 = __ballot(b1);
            if (lane == 0) { sup0[i] = m0; sup1[i] = m1; }
        }
    }
    __syncthreads();

    // ---- 6. greedy scan, transposed: registers + ballot only (wave 0) ----
    if (wid == 0) {
        u64 r0a = sup0[lane];
        u64 r1a = sup1[lane];
        const int  j2  = lane + 64;
        const bool hv2 = j2 < TOPK_PRE;
        u64 r0b = hv2 ? sup0[j2] : 0ull;
        u64 r1b = hv2 ? sup1[j2] : 0ull;
        bool alive_a = true;
        bool alive_b = hv2;

#pragma unroll 4
        for (int i = 0; i < 64; ++i) {
            u64 bal = __ballot(alive_a);
            if ((bal >> i) & 1ull) {
                alive_a = alive_a && !((r0a >> i) & 1ull);
                alive_b = alive_b && !((r0b >> i) & 1ull);
            }
        }
#pragma unroll 4
        for (int i = 64; i < TOPK_PRE; ++i) {
            u64 bal = __ballot(alive_b);
            if ((bal >> (i - 64)) & 1ull) {
                alive_a = alive_a && !((r1a >> (i - 64)) & 1ull);
                alive_b = alive_b && !((r1b >> (i - 64)) & 1ull);
            }
        }
        u64 B0 = __ballot(alive_a);
        u64 B1 = __ballot(alive_b);
        if (lane == 0) { keep0s = B0; keep1s = B1; }
    }
    __syncthreads();

    // ---- 7. write outputs: thread t takes the t-th kept row ----
    if (tid < TOPK_POST) {
        u64 K0 = keep0s, K1 = keep1s;
        int c0n = __popcll(K0);
        int idx = -1;
        if (tid < c0n) {
            u64 x = K0;
            for (int k = 0; k < tid; ++k) x &= x - 1;
            idx = __ffsll(x) - 1;
        } else {
            int t = tid - c0n;
            if (t < __popcll(K1)) {
                u64 x = K1;
                for (int k = 0; k < t; ++k) x &= x - 1;
                idx = 64 + __ffsll(x) - 1;
            }
        }
        size_t o = (size_t)row * TOPK_POST + (size_t)tid;
        float s = 0.0f, xa = 0.0f, ya = 0.0f, xb = 0.0f, yb = 0.0f;
        float lab = -1.0f, m = 0.0f;
        if (idx >= 0) {
            s = scs[idx];
            xa = x1s[idx]; ya = y1s[idx]; xb = x2s[idx]; yb = y2s[idx];
            lab = (float)labels[row];
            m = 1.0f;
        }
        out[o] = s;
        float* ob = out + 20480 + o * 4;
        ob[0] = xa; ob[1] = ya; ob[2] = xb; ob[3] = yb;
        out[102400 + o] = lab;
        out[122880 + o] = m;
    }
}

extern "C" void kernel_launch(void* const* d_in, const int* in_sizes, int n_in,
                              void* d_out, int out_size, void* d_ws, size_t ws_size,
                              hipStream_t stream) {
    const float* logits = (const float*)d_in[0];
    const float* boxes  = (const float*)d_in[1];
    const float* tsize  = (const float*)d_in[2];
    const int*   labels = (const int*)d_in[3];
    float* out = (float*)d_out;

    ovnms_kernel<<<dim3(1024), dim3(THREADS), 0, stream>>>(logits, boxes, tsize, labels, out);
}